// Round 2
// 248.621 us; speedup vs baseline: 1.0496x; 1.0496x over previous
//
#include <hip/hip_runtime.h>
#include <hip/hip_bf16.h>
#include <math.h>

typedef __attribute__((ext_vector_type(8))) short bf16x8;
typedef __attribute__((ext_vector_type(4))) float f32x4;

static __device__ inline ushort f2bf(float f) {
    union { float f; unsigned u; } v; v.f = f;
    unsigned r = (v.u + 0x7fff + ((v.u >> 16) & 1)) >> 16;   // RNE
    return (ushort)r;
}

#define GLD_LDS(g, l) \
    __builtin_amdgcn_global_load_lds( \
        (const __attribute__((address_space(1))) void*)(g), \
        (__attribute__((address_space(3))) void*)(l), 16, 0, 0)

// ---------------------------------------------------------------------------
// x fp32 -> bf16
// ---------------------------------------------------------------------------
__global__ __launch_bounds__(256) void convert_x(
    const float* __restrict__ x, ushort* __restrict__ xb)
{
    const size_t i = ((size_t)blockIdx.x * 256 + threadIdx.x) * 8;
    float4 a = *(const float4*)(x + i);
    float4 b = *(const float4*)(x + i + 4);
    bf16x8 t;
    t[0] = (short)f2bf(a.x); t[1] = (short)f2bf(a.y);
    t[2] = (short)f2bf(a.z); t[3] = (short)f2bf(a.w);
    t[4] = (short)f2bf(b.x); t[5] = (short)f2bf(b.y);
    t[6] = (short)f2bf(b.z); t[7] = (short)f2bf(b.w);
    *(bf16x8*)(xb + i) = t;
}

// ---------------------------------------------------------------------------
// Weights fp32 [K][N] -> Wt bf16 [4096][1024] transposed
// ---------------------------------------------------------------------------
__global__ __launch_bounds__(256) void prep_w(
    const float* __restrict__ Wq, const float* __restrict__ Wkv,
    const float* __restrict__ Wo, ushort* __restrict__ Wt)
{
    const int w = threadIdx.x >> 6;
    const int lane = threadIdx.x & 63;
    const int tile = blockIdx.x * 4 + w;
    const int r0 = (tile >> 4) << 6;
    const int k0 = (tile & 15) << 6;

    const float* src; int ld, c0;
    if (r0 < 1024)      { src = Wq;  ld = 1024; c0 = r0; }
    else if (r0 < 3072) { src = Wkv; ld = 2048; c0 = r0 - 1024; }
    else                { src = Wo;  ld = 1024; c0 = r0 - 3072; }

    ushort v[64];
    #pragma unroll
    for (int k = 0; k < 64; ++k)
        v[k] = f2bf(src[(size_t)(k0 + k) * ld + c0 + lane]);

    ushort* dst = Wt + (size_t)(r0 + lane) * 1024 + k0;
    #pragma unroll
    for (int k = 0; k < 64; k += 8) {
        bf16x8 t;
        #pragma unroll
        for (int j = 0; j < 8; ++j) t[j] = (short)v[k + j];
        *(bf16x8*)(dst + k) = t;
    }
}

// ---------------------------------------------------------------------------
// Phase-split counted-vmcnt GEMM: tile 128(M)x256(N), BK=64, 512 thr / 8 waves
// (2 wave-rows x 4 wave-cols; per-wave 64x64 = acc[4][4] frags).
// 4 phases per K-tile; B frags loaded once (phase 0) and held in regs.
// Stage schedule (per tile u): ph0: A(u+1) [dead buf], ph1/ph2: B halves(u+2)
// [live buf, B fully consumed in ph0, barrier-separated]. Boundary waits
// vmcnt(4) in steady state (= 2 newest stage groups in flight), vmcnt(0)
// only for the last two boundaries. LDS reads conflict-free via chunk^=row&7
// swizzle applied on the GLOBAL source (global_load_lds writes linearly).
// ---------------------------------------------------------------------------
#define STG_A(t) { ushort* d_ = &As[(t) & 1][ldst];                            \
    GLD_LDS(aS0 + (size_t)(t) * 64, d_);                                       \
    GLD_LDS(aS1 + (size_t)(t) * 64, d_ + 64 * 64); }
#define STG_B1(t) { ushort* d_ = &Bs[(t) & 1][ldst];                           \
    GLD_LDS(bS0 + (size_t)(t) * 64, d_);                                       \
    GLD_LDS(bS1 + (size_t)(t) * 64, d_ + 64 * 64); }
#define STG_B2(t) { ushort* d_ = &Bs[(t) & 1][128 * 64 + ldst];                \
    GLD_LDS(bS2 + (size_t)(t) * 64, d_);                                       \
    GLD_LDS(bS3 + (size_t)(t) * 64, d_ + 64 * 64); }

#define GEMM_PIPE(Aptr, Btptr, NXT, NWG)                                       \
    __shared__ ushort As[2][128 * 64];                                         \
    __shared__ ushort Bs[2][256 * 64];                                         \
    const int tid = threadIdx.x;                                               \
    const int lane = tid & 63;                                                 \
    const int w = tid >> 6;                                                    \
    const int l15 = lane & 15;                                                 \
    const int quad = lane >> 4;                                                \
    const int wm = w >> 2, wn = w & 3;                                         \
    const int cx = l15 & 7;                                                    \
    const int lin = blockIdx.y * (NXT) + blockIdx.x;                           \
    const int wg = (lin & 7) * ((NWG) >> 3) + (lin >> 3);                      \
    const int rowBase = (wg / (NXT)) * 128;                                    \
    const int colBase = (wg % (NXT)) * 256;                                    \
    const int sr = tid >> 3, sc = tid & 7;                                     \
    const int ldst = sr * 64 + sc * 8;                                         \
    const ushort* aS0 = (Aptr) + (size_t)(rowBase + sr) * 1024 + ((sc ^ (sr & 7)) << 3); \
    const ushort* aS1 = aS0 + (size_t)64 * 1024;                               \
    const ushort* bS0 = (Btptr) + (size_t)(colBase + sr) * 1024 + ((sc ^ (sr & 7)) << 3); \
    const ushort* bS1 = bS0 + (size_t)64 * 1024;                               \
    const ushort* bS2 = bS0 + (size_t)128 * 1024;                              \
    const ushort* bS3 = bS0 + (size_t)192 * 1024;                              \
    f32x4 acc[4][4];                                                           \
    _Pragma("unroll")                                                          \
    for (int i_ = 0; i_ < 4; ++i_)                                             \
        _Pragma("unroll")                                                      \
        for (int j_ = 0; j_ < 4; ++j_) acc[i_][j_] = (f32x4){0.f, 0.f, 0.f, 0.f}; \
    STG_A(0) STG_B1(0) STG_B2(0) STG_B1(1) STG_B2(1)                           \
    asm volatile("s_waitcnt vmcnt(4)" ::: "memory");                           \
    __builtin_amdgcn_s_barrier();                                              \
    asm volatile("" ::: "memory");                                             \
    _Pragma("unroll 1")                                                        \
    for (int u = 0; u < 16; ++u) {                                             \
        const ushort* aRd = &As[u & 1][(wm * 64 + l15) * 64];                  \
        const ushort* bRd = &Bs[u & 1][(wn * 64 + l15) * 64];                  \
        const int c0 = (quad ^ cx) << 3, c1 = ((4 | quad) ^ cx) << 3;          \
        bf16x8 bF0[4], bF1[4];                                                 \
        _Pragma("unroll")                                                      \
        for (int ni = 0; ni < 4; ++ni) {                                       \
            bF0[ni] = *(const bf16x8*)(bRd + ni * 1024 + c0);                  \
            bF1[ni] = *(const bf16x8*)(bRd + ni * 1024 + c1);                  \
        }                                                                      \
        bf16x8 a0 = *(const bf16x8*)(aRd + c0);                                \
        bf16x8 a1 = *(const bf16x8*)(aRd + c1);                                \
        if (u + 1 < 16) { STG_A(u + 1) }                                       \
        __builtin_amdgcn_s_barrier();                                          \
        asm volatile("s_waitcnt lgkmcnt(0)" ::: "memory");                     \
        __builtin_amdgcn_sched_barrier(0);                                     \
        __builtin_amdgcn_s_setprio(1);                                         \
        _Pragma("unroll")                                                      \
        for (int ni = 0; ni < 4; ++ni) {                                       \
            acc[0][ni] = __builtin_amdgcn_mfma_f32_16x16x32_bf16(a0, bF0[ni], acc[0][ni], 0, 0, 0); \
            acc[0][ni] = __builtin_amdgcn_mfma_f32_16x16x32_bf16(a1, bF1[ni], acc[0][ni], 0, 0, 0); \
        }                                                                      \
        __builtin_amdgcn_s_setprio(0);                                         \
        __builtin_amdgcn_s_barrier();                                          \
        asm volatile("" ::: "memory");                                         \
        _Pragma("unroll")                                                      \
        for (int q = 1; q < 4; ++q) {                                          \
            bf16x8 aa = *(const bf16x8*)(aRd + q * 1024 + c0);                 \
            bf16x8 ab = *(const bf16x8*)(aRd + q * 1024 + c1);                 \
            if (q == 1 && u + 2 < 16) { STG_B1(u + 2) }                        \
            if (q == 2 && u + 2 < 16) { STG_B2(u + 2) }                        \
            __builtin_amdgcn_s_barrier();                                      \
            asm volatile("s_waitcnt lgkmcnt(0)" ::: "memory");                 \
            __builtin_amdgcn_sched_barrier(0);                                 \
            __builtin_amdgcn_s_setprio(1);                                     \
            _Pragma("unroll")                                                  \
            for (int ni = 0; ni < 4; ++ni) {                                   \
                acc[q][ni] = __builtin_amdgcn_mfma_f32_16x16x32_bf16(aa, bF0[ni], acc[q][ni], 0, 0, 0); \
                acc[q][ni] = __builtin_amdgcn_mfma_f32_16x16x32_bf16(ab, bF1[ni], acc[q][ni], 0, 0, 0); \
            }                                                                  \
            __builtin_amdgcn_s_setprio(0);                                     \
            if (q == 3) {                                                      \
                if (u < 14) { asm volatile("s_waitcnt vmcnt(4)" ::: "memory"); } \
                else        { asm volatile("s_waitcnt vmcnt(0)" ::: "memory"); } \
            }                                                                  \
            __builtin_amdgcn_s_barrier();                                      \
            asm volatile("" ::: "memory");                                     \
        }                                                                      \
    }

// ---------------------------------------------------------------------------
// GEMM 1: xb x Wt[0:3072] -> Q (pre-scaled by 0.125*log2e), K in [bh][n][64];
//         V directly transposed into Vt [bh*64+d][2048]
// ---------------------------------------------------------------------------
__global__ __launch_bounds__(512, 2) void gemm_qkv(
    const ushort* __restrict__ A, const ushort* __restrict__ Bt,
    ushort* __restrict__ Qb, ushort* __restrict__ Kb, ushort* __restrict__ Vt)
{
    GEMM_PIPE(A, Bt, 12, 768)

    const int seg = colBase >> 10;          // 0=Q 1=K 2=V
    if (seg == 2) {
        #pragma unroll
        for (int mi = 0; mi < 4; ++mi) {
            #pragma unroll
            for (int ni = 0; ni < 4; ++ni) {
                const int c = (colBase + wn*64 + ni*16 + l15) & 1023;
                const int h = c >> 6, d = c & 63;
                const int m = rowBase + wm*64 + mi*16 + quad*4;
                const int b = m >> 11, nn = m & 2047;
                ushort4 v;
                v.x = f2bf(acc[mi][ni][0]); v.y = f2bf(acc[mi][ni][1]);
                v.z = f2bf(acc[mi][ni][2]); v.w = f2bf(acc[mi][ni][3]);
                *(ushort4*)(Vt + ((size_t)(b*16 + h)*64 + d)*2048 + nn) = v;
            }
        }
    } else {
        ushort* dst = seg ? Kb : Qb;
        // Q pre-scale: 1/sqrt(64) * log2(e)  (softmax runs in base-2 domain)
        const float sc2 = seg ? 1.0f : 0.18033688011112042f;
        #pragma unroll
        for (int mi = 0; mi < 4; ++mi) {
            #pragma unroll
            for (int ni = 0; ni < 4; ++ni) {
                const int c = (colBase + wn*64 + ni*16 + l15) & 1023;
                const int h = c >> 6, d = c & 63;
                #pragma unroll
                for (int r = 0; r < 4; ++r) {
                    const int m = rowBase + wm*64 + mi*16 + quad*4 + r;
                    const int b = m >> 11, nn = m & 2047;
                    dst[((((size_t)b*16 + h)*2048 + nn) << 6) + d] = f2bf(acc[mi][ni][r] * sc2);
                }
            }
        }
    }
}

// ---------------------------------------------------------------------------
// GEMM 2: Ob x Wt[3072:4096] + bo -> fp32 out
// ---------------------------------------------------------------------------
__global__ __launch_bounds__(512, 2) void gemm_out(
    const ushort* __restrict__ A, const ushort* __restrict__ Bt,
    const float* __restrict__ bo, float* __restrict__ out)
{
    GEMM_PIPE(A, Bt, 4, 256)

    #pragma unroll
    for (int mi = 0; mi < 4; ++mi) {
        #pragma unroll
        for (int ni = 0; ni < 4; ++ni) {
            const int n = colBase + wn*64 + ni*16 + l15;
            const float bb = bo[n];
            #pragma unroll
            for (int r = 0; r < 4; ++r) {
                const int m = rowBase + wm*64 + mi*16 + quad*4 + r;
                out[(size_t)m * 1024 + n] = acc[mi][ni][r] + bb;
            }
        }
    }
}

// ---------------------------------------------------------------------------
// Flash attention v5: unpaired q-tiles (grid 1024, qt-descending dispatch),
// double-buffered LDS K/V, S^T trick, skip-rescale on no-new-max.
// Block = 4 waves x 32 q-rows = one 128-row q-tile.
// ---------------------------------------------------------------------------
__device__ __forceinline__ bf16x8 lds_frag(const ushort* S, int row, int chunk) {
    return *(const bf16x8*)(S + row * 64 + ((chunk ^ (row & 7)) << 3));
}

__global__ __launch_bounds__(256, 2) void flash_mfma(
    const ushort* __restrict__ Qb,
    const ushort* __restrict__ Kb,
    const ushort* __restrict__ Vt,
    ushort* __restrict__ Ob)
{
    __shared__ ushort Ks[2][4096];
    __shared__ ushort Vs[2][4096];
    __shared__ ushort PsAll[4][32][72];

    const int tid = threadIdx.x;
    const int w = tid >> 6;
    const int lane = tid & 63;
    const int l15 = lane & 15;
    const int quad = lane >> 4;
    ushort (*Ps)[72] = PsAll[w];

    // 1024 blocks: [qt:4][bh_hi:3][xcd:3]; qt descending so long blocks first;
    // 8 heads per XCD slot (4MB K+V resident in one L2)
    const int blk = blockIdx.x;
    const int bh = ((blk & 7) << 3) | ((blk >> 3) & 7);
    const int qt = 15 - (blk >> 6);
    const int nt = 2 * qt + 2;
    const int rb0 = (qt << 7) + w * 32;

    // staging maps (xor-swizzled, 2x 16B chunks per thread per buffer)
    const int sr0 = tid >> 3, sr1 = sr0 + 32;
    const int cg0 = (tid & 7) ^ (sr0 & 7);
    const int cg1 = (tid & 7) ^ (sr1 & 7);
    const ushort* kgb = Kb + (size_t)bh * 131072;
    const ushort* vgb = Vt + (size_t)bh * 131072;

    // Q fragments (pre-scaled by 0.125*log2e)
    bf16x8 qf[2][2];
    #pragma unroll
    for (int mi = 0; mi < 2; ++mi) {
        const ushort* qp = Qb + ((size_t)bh * 2048 + rb0 + mi*16 + l15) * 64 + quad * 8;
        qf[mi][0] = *(const bf16x8*)qp;
        qf[mi][1] = *(const bf16x8*)(qp + 32);
    }

    bf16x8 bones;
    #pragma unroll
    for (int j = 0; j < 8; ++j) bones[j] = (short)0x3F80;   // bf16 1.0

    float m_r[2];
    f32x4 o[2][4], lacc[2];
    #pragma unroll
    for (int mi = 0; mi < 2; ++mi) {
        m_r[mi] = -INFINITY;
        lacc[mi] = (f32x4){0.f, 0.f, 0.f, 0.f};
        #pragma unroll
        for (int nb = 0; nb < 4; ++nb) o[mi][nb] = (f32x4){0.f, 0.f, 0.f, 0.f};
    }

    // prefetch tile 0 -> buf 0
    GLD_LDS(kgb + sr0*64 + cg0*8, &Ks[0][tid*8]);
    GLD_LDS(kgb + sr1*64 + cg1*8, &Ks[0][tid*8 + 2048]);
    GLD_LDS(vgb + (size_t)sr0*2048 + cg0*8, &Vs[0][tid*8]);
    GLD_LDS(vgb + (size_t)sr1*2048 + cg1*8, &Vs[0][tid*8 + 2048]);

    for (int t = 0; t < nt; ++t) {
        __syncthreads();                      // drains own GLDs; joins all waves
        const int cur = t & 1;
        if (t + 1 < nt) {
            const int jn = t + 1;
            ushort* kd = &Ks[cur ^ 1][tid * 8];
            ushort* vd = &Vs[cur ^ 1][tid * 8];
            GLD_LDS(kgb + (size_t)jn*4096 + sr0*64 + cg0*8, kd);
            GLD_LDS(kgb + (size_t)jn*4096 + sr1*64 + cg1*8, kd + 2048);
            GLD_LDS(vgb + (size_t)sr0*2048 + jn*64 + cg0*8, vd);
            GLD_LDS(vgb + (size_t)sr1*2048 + jn*64 + cg1*8, vd + 2048);
        }
        const int j0 = t << 6;
        if (j0 > rb0 + 31) continue;          // wave-uniform; barrier is at loop top

        const ushort* Ksb = Ks[cur];
        const ushort* Vsb = Vs[cur];

        // ---- S^T = K Q^T : [64 keys][32 qrows]; lane holds one qrow (l15) ----
        f32x4 St[2][4];                       // [mi][kb]
        #pragma unroll
        for (int kb = 0; kb < 4; ++kb) {
            bf16x8 ka = lds_frag(Ksb, kb*16 + l15, quad);
            bf16x8 kc = lds_frag(Ksb, kb*16 + l15, quad + 4);
            #pragma unroll
            for (int mi = 0; mi < 2; ++mi) {
                f32x4 s = (f32x4){0.f, 0.f, 0.f, 0.f};
                s = __builtin_amdgcn_mfma_f32_16x16x32_bf16(ka, qf[mi][0], s, 0, 0, 0);
                s = __builtin_amdgcn_mfma_f32_16x16x32_bf16(kc, qf[mi][1], s, 0, 0, 0);
                St[mi][kb] = s;
            }
        }

        #pragma unroll
        for (int mi = 0; mi < 2; ++mi) {
            const int qrow = rb0 + mi*16 + l15;
            if (j0 + 63 > rb0 + mi*16) {      // causal mask (straddling tiles only)
                #pragma unroll
                for (int kb = 0; kb < 4; ++kb) {
                    const int kbase = j0 + kb*16 + quad*4;
                    #pragma unroll
                    for (int r = 0; r < 4; ++r)
                        if (kbase + r > qrow) St[mi][kb][r] = -INFINITY;
                }
            }
            // lane-local max over this row's 16 scores + 2 cross-quad shuffles
            f32x4 mv = St[mi][0];
            #pragma unroll
            for (int kb = 1; kb < 4; ++kb)
                #pragma unroll
                for (int r = 0; r < 4; ++r) mv[r] = fmaxf(mv[r], St[mi][kb][r]);
            float mx = fmaxf(fmaxf(mv[0], mv[1]), fmaxf(mv[2], mv[3]));
            mx = fmaxf(mx, __shfl_xor(mx, 16));
            mx = fmaxf(mx, __shfl_xor(mx, 32));
            const float mold = m_r[mi];
            const float mnew = fmaxf(mold, mx);
            // skip-rescale: most tiles don't raise any row max
            if (__any(mnew > mold)) {
                m_r[mi] = mnew;
                const float corr = __builtin_amdgcn_exp2f(mold - mnew);
                // corr -> O-register layout (rows quad*4+r live in lanes 0..15)
                float ct[4];
                #pragma unroll
                for (int r = 0; r < 4; ++r) ct[r] = __shfl(corr, quad*4 + r);
                #pragma unroll
                for (int r = 0; r < 4; ++r) lacc[mi][r] *= ct[r];
                #pragma unroll
                for (int nb = 0; nb < 4; ++nb)
                    #pragma unroll
                    for (int r = 0; r < 4; ++r) o[mi][nb][r] *= ct[r];
            }
            // exp2 (base-2 domain) — mnew is a lane scalar for all 16 scores
            #pragma unroll
            for (int kb = 0; kb < 4; ++kb)
                #pragma unroll
                for (int r = 0; r < 4; ++r)
                    St[mi][kb][r] = __builtin_amdgcn_exp2f(St[mi][kb][r] - mnew);
            // pack 4 scores -> bf16x4, one ds_write_b64 per kb
            #pragma unroll
            for (int kb = 0; kb < 4; ++kb) {
                union { float f; unsigned u; } c0, c1, c2, c3;
                c0.f = St[mi][kb][0]; c1.f = St[mi][kb][1];
                c2.f = St[mi][kb][2]; c3.f = St[mi][kb][3];
                uint2 pk;
                pk.x = (c0.u >> 16) | (c1.u & 0xFFFF0000u);
                pk.y = (c2.u >> 16) | (c3.u & 0xFFFF0000u);
                *(uint2*)&Ps[mi*16 + l15][kb*16 + quad*4] = pk;
            }
        }

        // ---- O += P V ; l += P . 1 ----
        bf16x8 pf[2][2];
        #pragma unroll
        for (int mi = 0; mi < 2; ++mi) {
            pf[mi][0] = *(const bf16x8*)&Ps[mi*16 + l15][quad * 8];
            pf[mi][1] = *(const bf16x8*)&Ps[mi*16 + l15][32 + quad * 8];
        }
        #pragma unroll
        for (int mi = 0; mi < 2; ++mi) {
            lacc[mi] = __builtin_amdgcn_mfma_f32_16x16x32_bf16(pf[mi][0], bones, lacc[mi], 0, 0, 0);
            lacc[mi] = __builtin_amdgcn_mfma_f32_16x16x32_bf16(pf[mi][1], bones, lacc[mi], 0, 0, 0);
        }
        #pragma unroll
        for (int nb = 0; nb < 4; ++nb) {
            bf16x8 va = lds_frag(Vsb, nb*16 + l15, quad);
            bf16x8 vc = lds_frag(Vsb, nb*16 + l15, quad + 4);
            #pragma unroll
            for (int mi = 0; mi < 2; ++mi) {
                o[mi][nb] = __builtin_amdgcn_mfma_f32_16x16x32_bf16(pf[mi][0], va, o[mi][nb], 0, 0, 0);
                o[mi][nb] = __builtin_amdgcn_mfma_f32_16x16x32_bf16(pf[mi][1], vc, o[mi][nb], 0, 0, 0);
            }
        }
    }

    // ---- normalize + store O bf16 [b][n][h*64] ----
    const int b = bh >> 4, h = bh & 15;
    #pragma unroll
    for (int mi = 0; mi < 2; ++mi)
        #pragma unroll
        for (int r = 0; r < 4; ++r) {
            const int ig = rb0 + mi*16 + quad*4 + r;
            const float inv = 1.f / lacc[mi][r];
            ushort* op = Ob + ((size_t)(b * 2048 + ig)) * 1024 + h * 64 + l15;
            #pragma unroll
            for (int nb = 0; nb < 4; ++nb)
                op[nb * 16] = f2bf(o[mi][nb][r] * inv);
        }
}

// ---------------------------------------------------------------------------
extern "C" void kernel_launch(void* const* d_in, const int* in_sizes, int n_in,
                              void* d_out, int out_size, void* d_ws, size_t ws_size,
                              hipStream_t stream) {
    const float* x   = (const float*)d_in[0];
    const float* Wq  = (const float*)d_in[1];
    const float* Wkv = (const float*)d_in[2];
    const float* Wo  = (const float*)d_in[3];
    const float* bo  = (const float*)d_in[4];
    float* out = (float*)d_out;

    const size_t SEG = (size_t)8388608 * 2;   // 16 MB per bf16 [8192x1024]
    char* ws = (char*)d_ws;
    ushort* xb = (ushort*)(ws);
    ushort* Qb = (ushort*)(ws + SEG);
    ushort* Kb = (ushort*)(ws + SEG * 2);
    ushort* Vt = (ushort*)(ws + SEG * 3);     // [bh*64+d][2048]
    ushort* Ob = (ushort*)(ws + SEG * 4);
    ushort* Wt = (ushort*)(ws + SEG * 5);     // [4096][1024] bf16

    convert_x<<<dim3(4096), 256, 0, stream>>>(x, xb);
    prep_w<<<dim3(256), 256, 0, stream>>>(Wq, Wkv, Wo, Wt);
    gemm_qkv<<<dim3(12, 64), 512, 0, stream>>>(xb, Wt, Qb, Kb, Vt);
    flash_mfma<<<dim3(1024), 256, 0, stream>>>(Qb, Kb, Vt, Ob);
    gemm_out<<<dim3(4, 64), 512, 0, stream>>>(Ob, Wt + (size_t)3072 * 1024, bo, out);
}

// Round 3
// 245.769 us; speedup vs baseline: 1.0618x; 1.0116x over previous
//
#include <hip/hip_runtime.h>
#include <hip/hip_bf16.h>
#include <math.h>

typedef __attribute__((ext_vector_type(8))) short bf16x8;
typedef __attribute__((ext_vector_type(4))) float f32x4;

static __device__ inline ushort f2bf(float f) {
    union { float f; unsigned u; } v; v.f = f;
    unsigned r = (v.u + 0x7fff + ((v.u >> 16) & 1)) >> 16;   // RNE
    return (ushort)r;
}

#define GLD_LDS(g, l) \
    __builtin_amdgcn_global_load_lds( \
        (const __attribute__((address_space(1))) void*)(g), \
        (__attribute__((address_space(3))) void*)(l), 16, 0, 0)

// ---------------------------------------------------------------------------
// x fp32 -> bf16
// ---------------------------------------------------------------------------
__global__ __launch_bounds__(256) void convert_x(
    const float* __restrict__ x, ushort* __restrict__ xb)
{
    const size_t i = ((size_t)blockIdx.x * 256 + threadIdx.x) * 8;
    float4 a = *(const float4*)(x + i);
    float4 b = *(const float4*)(x + i + 4);
    bf16x8 t;
    t[0] = (short)f2bf(a.x); t[1] = (short)f2bf(a.y);
    t[2] = (short)f2bf(a.z); t[3] = (short)f2bf(a.w);
    t[4] = (short)f2bf(b.x); t[5] = (short)f2bf(b.y);
    t[6] = (short)f2bf(b.z); t[7] = (short)f2bf(b.w);
    *(bf16x8*)(xb + i) = t;
}

// ---------------------------------------------------------------------------
// Weights fp32 [K][N] -> Wt bf16 [4096][1024] transposed
// ---------------------------------------------------------------------------
__global__ __launch_bounds__(256) void prep_w(
    const float* __restrict__ Wq, const float* __restrict__ Wkv,
    const float* __restrict__ Wo, ushort* __restrict__ Wt)
{
    const int w = threadIdx.x >> 6;
    const int lane = threadIdx.x & 63;
    const int tile = blockIdx.x * 4 + w;
    const int r0 = (tile >> 4) << 6;
    const int k0 = (tile & 15) << 6;

    const float* src; int ld, c0;
    if (r0 < 1024)      { src = Wq;  ld = 1024; c0 = r0; }
    else if (r0 < 3072) { src = Wkv; ld = 2048; c0 = r0 - 1024; }
    else                { src = Wo;  ld = 1024; c0 = r0 - 3072; }

    ushort v[64];
    #pragma unroll
    for (int k = 0; k < 64; ++k)
        v[k] = f2bf(src[(size_t)(k0 + k) * ld + c0 + lane]);

    ushort* dst = Wt + (size_t)(r0 + lane) * 1024 + k0;
    #pragma unroll
    for (int k = 0; k < 64; k += 8) {
        bf16x8 t;
        #pragma unroll
        for (int j = 0; j < 8; ++j) t[j] = (short)v[k + j];
        *(bf16x8*)(dst + k) = t;
    }
}

// ---------------------------------------------------------------------------
// Phase-split counted-vmcnt GEMM: tile 128(M)x256(N), BK=64, 512 thr / 8 waves
// (2 wave-rows x 4 wave-cols; per-wave 64x64 = acc[4][4] frags).
// 2 phases per K-tile, 16 MFMA each (m201 granularity):
//   ph A: 12 ds_reads (8 B-frags + rows 0,1) + STG_A(u+1) [dead buf]
//         -> barrier -> lgkmcnt(0) -> 16 MFMA (acc rows 0,1) -> barrier
//   ph B: 4 ds_reads (rows 2,3) + STG_B1/B2(u+2) [live buf; safe: ph-A closing
//         barrier guarantees all waves' B(u) reads done]
//         -> barrier -> lgkmcnt(0) -> 16 MFMA (rows 2,3) -> vmcnt -> barrier
// Boundary waits vmcnt(4) in steady state (keep 4 newest = B(u+2) in flight),
// vmcnt(0) only for the last two boundaries. LDS conflict-free via chunk^=row&7
// swizzle applied on the GLOBAL source (global_load_lds writes linearly).
// ---------------------------------------------------------------------------
#define STG_A(t) { ushort* d_ = &As[(t) & 1][ldst];                            \
    GLD_LDS(aS0 + (size_t)(t) * 64, d_);                                       \
    GLD_LDS(aS1 + (size_t)(t) * 64, d_ + 64 * 64); }
#define STG_B1(t) { ushort* d_ = &Bs[(t) & 1][ldst];                           \
    GLD_LDS(bS0 + (size_t)(t) * 64, d_);                                       \
    GLD_LDS(bS1 + (size_t)(t) * 64, d_ + 64 * 64); }
#define STG_B2(t) { ushort* d_ = &Bs[(t) & 1][128 * 64 + ldst];                \
    GLD_LDS(bS2 + (size_t)(t) * 64, d_);                                       \
    GLD_LDS(bS3 + (size_t)(t) * 64, d_ + 64 * 64); }

#define GEMM_PIPE(Aptr, Btptr, NXT, NWG)                                       \
    __shared__ ushort As[2][128 * 64];                                         \
    __shared__ ushort Bs[2][256 * 64];                                         \
    const int tid = threadIdx.x;                                               \
    const int lane = tid & 63;                                                 \
    const int w = tid >> 6;                                                    \
    const int l15 = lane & 15;                                                 \
    const int quad = lane >> 4;                                                \
    const int wm = w >> 2, wn = w & 3;                                         \
    const int cx = l15 & 7;                                                    \
    const int lin = blockIdx.y * (NXT) + blockIdx.x;                           \
    const int wg = (lin & 7) * ((NWG) >> 3) + (lin >> 3);                      \
    const int rowBase = (wg / (NXT)) * 128;                                    \
    const int colBase = (wg % (NXT)) * 256;                                    \
    const int sr = tid >> 3, sc = tid & 7;                                     \
    const int ldst = sr * 64 + sc * 8;                                         \
    const ushort* aS0 = (Aptr) + (size_t)(rowBase + sr) * 1024 + ((sc ^ (sr & 7)) << 3); \
    const ushort* aS1 = aS0 + (size_t)64 * 1024;                               \
    const ushort* bS0 = (Btptr) + (size_t)(colBase + sr) * 1024 + ((sc ^ (sr & 7)) << 3); \
    const ushort* bS1 = bS0 + (size_t)64 * 1024;                               \
    const ushort* bS2 = bS0 + (size_t)128 * 1024;                              \
    const ushort* bS3 = bS0 + (size_t)192 * 1024;                              \
    f32x4 acc[4][4];                                                           \
    _Pragma("unroll")                                                          \
    for (int i_ = 0; i_ < 4; ++i_)                                             \
        _Pragma("unroll")                                                      \
        for (int j_ = 0; j_ < 4; ++j_) acc[i_][j_] = (f32x4){0.f, 0.f, 0.f, 0.f}; \
    STG_A(0) STG_B1(0) STG_B2(0) STG_B1(1) STG_B2(1)                           \
    asm volatile("s_waitcnt vmcnt(4)" ::: "memory");                           \
    __builtin_amdgcn_s_barrier();                                              \
    asm volatile("" ::: "memory");                                             \
    _Pragma("unroll 1")                                                        \
    for (int u = 0; u < 16; ++u) {                                             \
        const ushort* aRd = &As[u & 1][(wm * 64 + l15) * 64];                  \
        const ushort* bRd = &Bs[u & 1][(wn * 64 + l15) * 64];                  \
        const int c0 = (quad ^ cx) << 3, c1 = ((4 | quad) ^ cx) << 3;          \
        /* ---- phase A: B-frags + A rows 0,1 ---- */                          \
        bf16x8 bF0[4], bF1[4];                                                 \
        _Pragma("unroll")                                                      \
        for (int ni = 0; ni < 4; ++ni) {                                       \
            bF0[ni] = *(const bf16x8*)(bRd + ni * 1024 + c0);                  \
            bF1[ni] = *(const bf16x8*)(bRd + ni * 1024 + c1);                  \
        }                                                                      \
        bf16x8 a00 = *(const bf16x8*)(aRd + c0);                               \
        bf16x8 a01 = *(const bf16x8*)(aRd + c1);                               \
        bf16x8 a10 = *(const bf16x8*)(aRd + 1024 + c0);                        \
        bf16x8 a11 = *(const bf16x8*)(aRd + 1024 + c1);                        \
        if (u + 1 < 16) { STG_A(u + 1) }                                       \
        __builtin_amdgcn_s_barrier();                                          \
        asm volatile("s_waitcnt lgkmcnt(0)" ::: "memory");                     \
        __builtin_amdgcn_sched_barrier(0);                                     \
        __builtin_amdgcn_s_setprio(1);                                         \
        _Pragma("unroll")                                                      \
        for (int ni = 0; ni < 4; ++ni) {                                       \
            acc[0][ni] = __builtin_amdgcn_mfma_f32_16x16x32_bf16(a00, bF0[ni], acc[0][ni], 0, 0, 0); \
            acc[0][ni] = __builtin_amdgcn_mfma_f32_16x16x32_bf16(a01, bF1[ni], acc[0][ni], 0, 0, 0); \
        }                                                                      \
        _Pragma("unroll")                                                      \
        for (int ni = 0; ni < 4; ++ni) {                                       \
            acc[1][ni] = __builtin_amdgcn_mfma_f32_16x16x32_bf16(a10, bF0[ni], acc[1][ni], 0, 0, 0); \
            acc[1][ni] = __builtin_amdgcn_mfma_f32_16x16x32_bf16(a11, bF1[ni], acc[1][ni], 0, 0, 0); \
        }                                                                      \
        __builtin_amdgcn_s_setprio(0);                                         \
        __builtin_amdgcn_s_barrier();                                          \
        asm volatile("" ::: "memory");                                         \
        /* ---- phase B: A rows 2,3 ---- */                                    \
        bf16x8 a20 = *(const bf16x8*)(aRd + 2 * 1024 + c0);                    \
        bf16x8 a21 = *(const bf16x8*)(aRd + 2 * 1024 + c1);                    \
        bf16x8 a30 = *(const bf16x8*)(aRd + 3 * 1024 + c0);                    \
        bf16x8 a31 = *(const bf16x8*)(aRd + 3 * 1024 + c1);                    \
        if (u + 2 < 16) { STG_B1(u + 2) STG_B2(u + 2) }                        \
        __builtin_amdgcn_s_barrier();                                          \
        asm volatile("s_waitcnt lgkmcnt(0)" ::: "memory");                     \
        __builtin_amdgcn_sched_barrier(0);                                     \
        __builtin_amdgcn_s_setprio(1);                                         \
        _Pragma("unroll")                                                      \
        for (int ni = 0; ni < 4; ++ni) {                                       \
            acc[2][ni] = __builtin_amdgcn_mfma_f32_16x16x32_bf16(a20, bF0[ni], acc[2][ni], 0, 0, 0); \
            acc[2][ni] = __builtin_amdgcn_mfma_f32_16x16x32_bf16(a21, bF1[ni], acc[2][ni], 0, 0, 0); \
        }                                                                      \
        _Pragma("unroll")                                                      \
        for (int ni = 0; ni < 4; ++ni) {                                       \
            acc[3][ni] = __builtin_amdgcn_mfma_f32_16x16x32_bf16(a30, bF0[ni], acc[3][ni], 0, 0, 0); \
            acc[3][ni] = __builtin_amdgcn_mfma_f32_16x16x32_bf16(a31, bF1[ni], acc[3][ni], 0, 0, 0); \
        }                                                                      \
        __builtin_amdgcn_s_setprio(0);                                         \
        if (u < 14) { asm volatile("s_waitcnt vmcnt(4)" ::: "memory"); }       \
        else        { asm volatile("s_waitcnt vmcnt(0)" ::: "memory"); }       \
        __builtin_amdgcn_s_barrier();                                          \
        asm volatile("" ::: "memory");                                         \
    }

// ---------------------------------------------------------------------------
// GEMM 1: xb x Wt[0:3072] -> Q (pre-scaled by 0.125*log2e), K in [bh][n][64];
//         V directly transposed into Vt [bh*64+d][2048]
// ---------------------------------------------------------------------------
__global__ __launch_bounds__(512, 2) void gemm_qkv(
    const ushort* __restrict__ A, const ushort* __restrict__ Bt,
    ushort* __restrict__ Qb, ushort* __restrict__ Kb, ushort* __restrict__ Vt)
{
    GEMM_PIPE(A, Bt, 12, 768)

    const int seg = colBase >> 10;          // 0=Q 1=K 2=V
    if (seg == 2) {
        #pragma unroll
        for (int mi = 0; mi < 4; ++mi) {
            #pragma unroll
            for (int ni = 0; ni < 4; ++ni) {
                const int c = (colBase + wn*64 + ni*16 + l15) & 1023;
                const int h = c >> 6, d = c & 63;
                const int m = rowBase + wm*64 + mi*16 + quad*4;
                const int b = m >> 11, nn = m & 2047;
                ushort4 v;
                v.x = f2bf(acc[mi][ni][0]); v.y = f2bf(acc[mi][ni][1]);
                v.z = f2bf(acc[mi][ni][2]); v.w = f2bf(acc[mi][ni][3]);
                *(ushort4*)(Vt + ((size_t)(b*16 + h)*64 + d)*2048 + nn) = v;
            }
        }
    } else {
        ushort* dst = seg ? Kb : Qb;
        // Q pre-scale: 1/sqrt(64) * log2(e)  (softmax runs in base-2 domain)
        const float sc2 = seg ? 1.0f : 0.18033688011112042f;
        #pragma unroll
        for (int mi = 0; mi < 4; ++mi) {
            #pragma unroll
            for (int ni = 0; ni < 4; ++ni) {
                const int c = (colBase + wn*64 + ni*16 + l15) & 1023;
                const int h = c >> 6, d = c & 63;
                #pragma unroll
                for (int r = 0; r < 4; ++r) {
                    const int m = rowBase + wm*64 + mi*16 + quad*4 + r;
                    const int b = m >> 11, nn = m & 2047;
                    dst[((((size_t)b*16 + h)*2048 + nn) << 6) + d] = f2bf(acc[mi][ni][r] * sc2);
                }
            }
        }
    }
}

// ---------------------------------------------------------------------------
// GEMM 2: Ob x Wt[3072:4096] + bo -> fp32 out
// ---------------------------------------------------------------------------
__global__ __launch_bounds__(512, 2) void gemm_out(
    const ushort* __restrict__ A, const ushort* __restrict__ Bt,
    const float* __restrict__ bo, float* __restrict__ out)
{
    GEMM_PIPE(A, Bt, 4, 256)

    #pragma unroll
    for (int mi = 0; mi < 4; ++mi) {
        #pragma unroll
        for (int ni = 0; ni < 4; ++ni) {
            const int n = colBase + wn*64 + ni*16 + l15;
            const float bb = bo[n];
            #pragma unroll
            for (int r = 0; r < 4; ++r) {
                const int m = rowBase + wm*64 + mi*16 + quad*4 + r;
                out[(size_t)m * 1024 + n] = acc[mi][ni][r] + bb;
            }
        }
    }
}

// ---------------------------------------------------------------------------
// Flash attention v5: unpaired q-tiles (grid 1024, qt-descending dispatch),
// double-buffered LDS K/V, S^T trick, skip-rescale on no-new-max.
// Block = 4 waves x 32 q-rows = one 128-row q-tile.
// ---------------------------------------------------------------------------
__device__ __forceinline__ bf16x8 lds_frag(const ushort* S, int row, int chunk) {
    return *(const bf16x8*)(S + row * 64 + ((chunk ^ (row & 7)) << 3));
}

__global__ __launch_bounds__(256, 2) void flash_mfma(
    const ushort* __restrict__ Qb,
    const ushort* __restrict__ Kb,
    const ushort* __restrict__ Vt,
    ushort* __restrict__ Ob)
{
    __shared__ ushort Ks[2][4096];
    __shared__ ushort Vs[2][4096];
    __shared__ ushort PsAll[4][32][72];

    const int tid = threadIdx.x;
    const int w = tid >> 6;
    const int lane = tid & 63;
    const int l15 = lane & 15;
    const int quad = lane >> 4;
    ushort (*Ps)[72] = PsAll[w];

    // 1024 blocks: [qt:4][bh_hi:3][xcd:3]; qt descending so long blocks first;
    // 8 heads per XCD slot (4MB K+V resident in one L2)
    const int blk = blockIdx.x;
    const int bh = ((blk & 7) << 3) | ((blk >> 3) & 7);
    const int qt = 15 - (blk >> 6);
    const int nt = 2 * qt + 2;
    const int rb0 = (qt << 7) + w * 32;

    // staging maps (xor-swizzled, 2x 16B chunks per thread per buffer)
    const int sr0 = tid >> 3, sr1 = sr0 + 32;
    const int cg0 = (tid & 7) ^ (sr0 & 7);
    const int cg1 = (tid & 7) ^ (sr1 & 7);
    const ushort* kgb = Kb + (size_t)bh * 131072;
    const ushort* vgb = Vt + (size_t)bh * 131072;

    // Q fragments (pre-scaled by 0.125*log2e)
    bf16x8 qf[2][2];
    #pragma unroll
    for (int mi = 0; mi < 2; ++mi) {
        const ushort* qp = Qb + ((size_t)bh * 2048 + rb0 + mi*16 + l15) * 64 + quad * 8;
        qf[mi][0] = *(const bf16x8*)qp;
        qf[mi][1] = *(const bf16x8*)(qp + 32);
    }

    bf16x8 bones;
    #pragma unroll
    for (int j = 0; j < 8; ++j) bones[j] = (short)0x3F80;   // bf16 1.0

    float m_r[2];
    f32x4 o[2][4], lacc[2];
    #pragma unroll
    for (int mi = 0; mi < 2; ++mi) {
        m_r[mi] = -INFINITY;
        lacc[mi] = (f32x4){0.f, 0.f, 0.f, 0.f};
        #pragma unroll
        for (int nb = 0; nb < 4; ++nb) o[mi][nb] = (f32x4){0.f, 0.f, 0.f, 0.f};
    }

    // prefetch tile 0 -> buf 0
    GLD_LDS(kgb + sr0*64 + cg0*8, &Ks[0][tid*8]);
    GLD_LDS(kgb + sr1*64 + cg1*8, &Ks[0][tid*8 + 2048]);
    GLD_LDS(vgb + (size_t)sr0*2048 + cg0*8, &Vs[0][tid*8]);
    GLD_LDS(vgb + (size_t)sr1*2048 + cg1*8, &Vs[0][tid*8 + 2048]);

    for (int t = 0; t < nt; ++t) {
        __syncthreads();                      // drains own GLDs; joins all waves
        const int cur = t & 1;
        if (t + 1 < nt) {
            const int jn = t + 1;
            ushort* kd = &Ks[cur ^ 1][tid * 8];
            ushort* vd = &Vs[cur ^ 1][tid * 8];
            GLD_LDS(kgb + (size_t)jn*4096 + sr0*64 + cg0*8, kd);
            GLD_LDS(kgb + (size_t)jn*4096 + sr1*64 + cg1*8, kd + 2048);
            GLD_LDS(vgb + (size_t)sr0*2048 + jn*64 + cg0*8, vd);
            GLD_LDS(vgb + (size_t)sr1*2048 + jn*64 + cg1*8, vd + 2048);
        }
        const int j0 = t << 6;
        if (j0 > rb0 + 31) continue;          // wave-uniform; barrier is at loop top

        const ushort* Ksb = Ks[cur];
        const ushort* Vsb = Vs[cur];

        // ---- S^T = K Q^T : [64 keys][32 qrows]; lane holds one qrow (l15) ----
        f32x4 St[2][4];                       // [mi][kb]
        #pragma unroll
        for (int kb = 0; kb < 4; ++kb) {
            bf16x8 ka = lds_frag(Ksb, kb*16 + l15, quad);
            bf16x8 kc = lds_frag(Ksb, kb*16 + l15, quad + 4);
            #pragma unroll
            for (int mi = 0; mi < 2; ++mi) {
                f32x4 s = (f32x4){0.f, 0.f, 0.f, 0.f};
                s = __builtin_amdgcn_mfma_f32_16x16x32_bf16(ka, qf[mi][0], s, 0, 0, 0);
                s = __builtin_amdgcn_mfma_f32_16x16x32_bf16(kc, qf[mi][1], s, 0, 0, 0);
                St[mi][kb] = s;
            }
        }

        #pragma unroll
        for (int mi = 0; mi < 2; ++mi) {
            const int qrow = rb0 + mi*16 + l15;
            if (j0 + 63 > rb0 + mi*16) {      // causal mask (straddling tiles only)
                #pragma unroll
                for (int kb = 0; kb < 4; ++kb) {
                    const int kbase = j0 + kb*16 + quad*4;
                    #pragma unroll
                    for (int r = 0; r < 4; ++r)
                        if (kbase + r > qrow) St[mi][kb][r] = -INFINITY;
                }
            }
            // lane-local max over this row's 16 scores + 2 cross-quad shuffles
            f32x4 mv = St[mi][0];
            #pragma unroll
            for (int kb = 1; kb < 4; ++kb)
                #pragma unroll
                for (int r = 0; r < 4; ++r) mv[r] = fmaxf(mv[r], St[mi][kb][r]);
            float mx = fmaxf(fmaxf(mv[0], mv[1]), fmaxf(mv[2], mv[3]));
            mx = fmaxf(mx, __shfl_xor(mx, 16));
            mx = fmaxf(mx, __shfl_xor(mx, 32));
            const float mold = m_r[mi];
            const float mnew = fmaxf(mold, mx);
            // skip-rescale: most tiles don't raise any row max
            if (__any(mnew > mold)) {
                m_r[mi] = mnew;
                const float corr = __builtin_amdgcn_exp2f(mold - mnew);
                // corr -> O-register layout (rows quad*4+r live in lanes 0..15)
                float ct[4];
                #pragma unroll
                for (int r = 0; r < 4; ++r) ct[r] = __shfl(corr, quad*4 + r);
                #pragma unroll
                for (int r = 0; r < 4; ++r) lacc[mi][r] *= ct[r];
                #pragma unroll
                for (int nb = 0; nb < 4; ++nb)
                    #pragma unroll
                    for (int r = 0; r < 4; ++r) o[mi][nb][r] *= ct[r];
            }
            // exp2 (base-2 domain) — mnew is a lane scalar for all 16 scores
            #pragma unroll
            for (int kb = 0; kb < 4; ++kb)
                #pragma unroll
                for (int r = 0; r < 4; ++r)
                    St[mi][kb][r] = __builtin_amdgcn_exp2f(St[mi][kb][r] - mnew);
            // pack 4 scores -> bf16x4, one ds_write_b64 per kb
            #pragma unroll
            for (int kb = 0; kb < 4; ++kb) {
                union { float f; unsigned u; } c0, c1, c2, c3;
                c0.f = St[mi][kb][0]; c1.f = St[mi][kb][1];
                c2.f = St[mi][kb][2]; c3.f = St[mi][kb][3];
                uint2 pk;
                pk.x = (c0.u >> 16) | (c1.u & 0xFFFF0000u);
                pk.y = (c2.u >> 16) | (c3.u & 0xFFFF0000u);
                *(uint2*)&Ps[mi*16 + l15][kb*16 + quad*4] = pk;
            }
        }

        // ---- O += P V ; l += P . 1 ----
        bf16x8 pf[2][2];
        #pragma unroll
        for (int mi = 0; mi < 2; ++mi) {
            pf[mi][0] = *(const bf16x8*)&Ps[mi*16 + l15][quad * 8];
            pf[mi][1] = *(const bf16x8*)&Ps[mi*16 + l15][32 + quad * 8];
        }
        #pragma unroll
        for (int mi = 0; mi < 2; ++mi) {
            lacc[mi] = __builtin_amdgcn_mfma_f32_16x16x32_bf16(pf[mi][0], bones, lacc[mi], 0, 0, 0);
            lacc[mi] = __builtin_amdgcn_mfma_f32_16x16x32_bf16(pf[mi][1], bones, lacc[mi], 0, 0, 0);
        }
        #pragma unroll
        for (int nb = 0; nb < 4; ++nb) {
            bf16x8 va = lds_frag(Vsb, nb*16 + l15, quad);
            bf16x8 vc = lds_frag(Vsb, nb*16 + l15, quad + 4);
            #pragma unroll
            for (int mi = 0; mi < 2; ++mi) {
                o[mi][nb] = __builtin_amdgcn_mfma_f32_16x16x32_bf16(pf[mi][0], va, o[mi][nb], 0, 0, 0);
                o[mi][nb] = __builtin_amdgcn_mfma_f32_16x16x32_bf16(pf[mi][1], vc, o[mi][nb], 0, 0, 0);
            }
        }
    }

    // ---- normalize + store O bf16 [b][n][h*64] ----
    const int b = bh >> 4, h = bh & 15;
    #pragma unroll
    for (int mi = 0; mi < 2; ++mi)
        #pragma unroll
        for (int r = 0; r < 4; ++r) {
            const int ig = rb0 + mi*16 + quad*4 + r;
            const float inv = 1.f / lacc[mi][r];
            ushort* op = Ob + ((size_t)(b * 2048 + ig)) * 1024 + h * 64 + l15;
            #pragma unroll
            for (int nb = 0; nb < 4; ++nb)
                op[nb * 16] = f2bf(o[mi][nb][r] * inv);
        }
}

// ---------------------------------------------------------------------------
extern "C" void kernel_launch(void* const* d_in, const int* in_sizes, int n_in,
                              void* d_out, int out_size, void* d_ws, size_t ws_size,
                              hipStream_t stream) {
    const float* x   = (const float*)d_in[0];
    const float* Wq  = (const float*)d_in[1];
    const float* Wkv = (const float*)d_in[2];
    const float* Wo  = (const float*)d_in[3];
    const float* bo  = (const float*)d_in[4];
    float* out = (float*)d_out;

    const size_t SEG = (size_t)8388608 * 2;   // 16 MB per bf16 [8192x1024]
    char* ws = (char*)d_ws;
    ushort* xb = (ushort*)(ws);
    ushort* Qb = (ushort*)(ws + SEG);
    ushort* Kb = (ushort*)(ws + SEG * 2);
    ushort* Vt = (ushort*)(ws + SEG * 3);     // [bh*64+d][2048]
    ushort* Ob = (ushort*)(ws + SEG * 4);
    ushort* Wt = (ushort*)(ws + SEG * 5);     // [4096][1024] bf16

    convert_x<<<dim3(4096), 256, 0, stream>>>(x, xb);
    prep_w<<<dim3(256), 256, 0, stream>>>(Wq, Wkv, Wo, Wt);
    gemm_qkv<<<dim3(12, 64), 512, 0, stream>>>(xb, Wt, Qb, Kb, Vt);
    flash_mfma<<<dim3(1024), 256, 0, stream>>>(Qb, Kb, Vt, Ob);
    gemm_out<<<dim3(4, 64), 512, 0, stream>>>(Ob, Wt + (size_t)3072 * 1024, bo, out);
}